// Round 5
// baseline (274.542 us; speedup 1.0000x reference)
//
#include <hip/hip_runtime.h>

#define NBLOCKS 4096
#define NTHREADS 256
// Each block-tile: NTHREADS threads x 4 float4 = 1024 float4 = 16 KB per array.
#define TILE_V4 (NTHREADS * 4)

typedef float vf4 __attribute__((ext_vector_type(4)));

__global__ __launch_bounds__(NTHREADS) void loss1_partial(
    const float* __restrict__ x, const float* __restrict__ y,
    long long n, float* __restrict__ psum, int* __restrict__ pcnt) {
    const long long nvec = n >> 2;
    const long long ntiles = nvec / TILE_V4;   // full 16KB tiles
    const vf4* __restrict__ x4 = (const vf4*)x;
    const vf4* __restrict__ y4 = (const vf4*)y;

    float s = 0.0f;
    int c = 0;

    // R3 structure minus the nontemporal hint (single-variable A/B):
    // contiguous 16KB-per-array tiles, plain cached loads for both streams.
    for (long long t = blockIdx.x; t < ntiles; t += gridDim.x) {
        long long p = t * TILE_V4 + threadIdx.x;
        vf4 a0 = x4[p];
        vf4 a1 = x4[p + NTHREADS];
        vf4 a2 = x4[p + 2 * NTHREADS];
        vf4 a3 = x4[p + 3 * NTHREADS];
        vf4 b0 = y4[p];
        vf4 b1 = y4[p + NTHREADS];
        vf4 b2 = y4[p + 2 * NTHREADS];
        vf4 b3 = y4[p + 3 * NTHREADS];

        #pragma unroll
        for (int k = 0; k < 4; ++k) {
            s += (a0[k] > b0[k]) ? (a0[k] - b0[k]) : 0.0f;  c += (a0[k] > b0[k]);
            s += (a1[k] > b1[k]) ? (a1[k] - b1[k]) : 0.0f;  c += (a1[k] > b1[k]);
            s += (a2[k] > b2[k]) ? (a2[k] - b2[k]) : 0.0f;  c += (a2[k] > b2[k]);
            s += (a3[k] > b3[k]) ? (a3[k] - b3[k]) : 0.0f;  c += (a3[k] > b3[k]);
        }
    }

    // float4 tail beyond the last full tile (none for this shape)
    {
        long long gtid = (long long)blockIdx.x * blockDim.x + threadIdx.x;
        long long gstride = (long long)gridDim.x * blockDim.x;
        for (long long i = ntiles * TILE_V4 + gtid; i < nvec; i += gstride) {
            vf4 a = x4[i];
            vf4 b = y4[i];
            #pragma unroll
            for (int k = 0; k < 4; ++k) {
                s += (a[k] > b[k]) ? (a[k] - b[k]) : 0.0f;  c += (a[k] > b[k]);
            }
        }
        if (gtid == 0) {
            for (long long j = nvec << 2; j < n; ++j) {
                float d = x[j] - y[j];
                if (x[j] > y[j]) { s += d; c += 1; }
            }
        }
    }

    // wave-64 shuffle reduction
    #pragma unroll
    for (int off = 32; off > 0; off >>= 1) {
        s += __shfl_down(s, off, 64);
        c += __shfl_down(c, off, 64);
    }

    __shared__ float ss[NTHREADS / 64];
    __shared__ int   sc[NTHREADS / 64];
    int lane = threadIdx.x & 63;
    int wave = threadIdx.x >> 6;
    if (lane == 0) { ss[wave] = s; sc[wave] = c; }
    __syncthreads();
    if (threadIdx.x == 0) {
        float ts = 0.0f; int tc = 0;
        #pragma unroll
        for (int w = 0; w < NTHREADS / 64; ++w) { ts += ss[w]; tc += sc[w]; }
        psum[blockIdx.x] = ts;
        pcnt[blockIdx.x] = tc;
    }
}

__global__ __launch_bounds__(1024) void loss1_final(
    const float* __restrict__ psum, const int* __restrict__ pcnt,
    int nparts, float* __restrict__ out) {
    int tid = threadIdx.x;
    float s = 0.0f;
    int c = 0;
    for (int i = tid; i < nparts; i += 1024) {
        s += psum[i];
        c += pcnt[i];
    }
    #pragma unroll
    for (int off = 32; off > 0; off >>= 1) {
        s += __shfl_down(s, off, 64);
        c += __shfl_down(c, off, 64);
    }
    __shared__ float ss[16];
    __shared__ int   sc[16];
    int lane = tid & 63;
    int wave = tid >> 6;
    if (lane == 0) { ss[wave] = s; sc[wave] = c; }
    __syncthreads();
    if (tid == 0) {
        float ts = 0.0f; int tc = 0;
        #pragma unroll
        for (int w = 0; w < 16; ++w) { ts += ss[w]; tc += sc[w]; }
        out[0] = (tc > 0) ? (ts / (float)tc) : 0.0f;
    }
}

extern "C" void kernel_launch(void* const* d_in, const int* in_sizes, int n_in,
                              void* d_out, int out_size, void* d_ws, size_t ws_size,
                              hipStream_t stream) {
    const float* x = (const float*)d_in[0];
    const float* y = (const float*)d_in[1];
    long long n = (long long)in_sizes[0];

    float* psum = (float*)d_ws;
    int*   pcnt = (int*)((char*)d_ws + NBLOCKS * sizeof(float));

    loss1_partial<<<NBLOCKS, NTHREADS, 0, stream>>>(x, y, n, psum, pcnt);
    loss1_final<<<1, 1024, 0, stream>>>(psum, pcnt, NBLOCKS, (float*)d_out);
}

// Round 6
// 259.324 us; speedup vs baseline: 1.0587x; 1.0587x over previous
//
#include <hip/hip_runtime.h>

#define NBLOCKS 2048
#define NTHREADS 256
// Per-tile: NTHREADS threads x 4 float4 = 1024 float4 = 16 KB per array.
#define TILE_V4 (NTHREADS * 4)

typedef float vf4 __attribute__((ext_vector_type(4)));

// Async global->LDS DMA (gfx950, width=16). LDS dest is wave-uniform base +
// lane*16; our layout is contiguous in threadIdx order, which satisfies it.
__device__ __forceinline__ void stage16(const vf4* g, vf4* l) {
    __builtin_amdgcn_global_load_lds(
        (const __attribute__((address_space(1))) void*)g,
        (__attribute__((address_space(3))) void*)l,
        16, 0, 0);
}

__global__ __launch_bounds__(NTHREADS) void loss1_partial(
    const float* __restrict__ x, const float* __restrict__ y,
    long long n, float* __restrict__ psum, int* __restrict__ pcnt) {
    const long long nvec = n >> 2;
    const long long ntiles = nvec / TILE_V4;
    const vf4* __restrict__ x4 = (const vf4*)x;
    const vf4* __restrict__ y4 = (const vf4*)y;

    __shared__ vf4 ybuf[TILE_V4];   // 16 KB -> LDS allows 10 blocks/CU (wave cap 8)

    float s = 0.0f;
    int c = 0;

    // Two read paths in parallel:
    //   x: nontemporal loads -> VGPR (R3's winning config, ~1.8 TB/s)
    //   y: global_load_lds DMA -> LDS (separate request queue from the
    //      VGPR-return path; tests whether outstanding-line budgets add)
    for (long long t = blockIdx.x; t < ntiles; t += gridDim.x) {
        long long p = t * TILE_V4 + threadIdx.x;

        #pragma unroll
        for (int u = 0; u < 4; ++u)
            stage16(&y4[p + u * NTHREADS], &ybuf[threadIdx.x + u * NTHREADS]);

        vf4 a0 = __builtin_nontemporal_load(&x4[p]);
        vf4 a1 = __builtin_nontemporal_load(&x4[p + NTHREADS]);
        vf4 a2 = __builtin_nontemporal_load(&x4[p + 2 * NTHREADS]);
        vf4 a3 = __builtin_nontemporal_load(&x4[p + 3 * NTHREADS]);

        __syncthreads();   // drains vmcnt: DMA stage + x loads complete

        vf4 b0 = ybuf[threadIdx.x];
        vf4 b1 = ybuf[threadIdx.x + NTHREADS];
        vf4 b2 = ybuf[threadIdx.x + 2 * NTHREADS];
        vf4 b3 = ybuf[threadIdx.x + 3 * NTHREADS];

        #pragma unroll
        for (int k = 0; k < 4; ++k) {
            s += (a0[k] > b0[k]) ? (a0[k] - b0[k]) : 0.0f;  c += (a0[k] > b0[k]);
            s += (a1[k] > b1[k]) ? (a1[k] - b1[k]) : 0.0f;  c += (a1[k] > b1[k]);
            s += (a2[k] > b2[k]) ? (a2[k] - b2[k]) : 0.0f;  c += (a2[k] > b2[k]);
            s += (a3[k] > b3[k]) ? (a3[k] - b3[k]) : 0.0f;  c += (a3[k] > b3[k]);
        }

        __syncthreads();   // protect ybuf before next tile's DMA overwrites it
    }

    // float4 tail beyond the last full tile (none for this shape)
    {
        long long gtid = (long long)blockIdx.x * blockDim.x + threadIdx.x;
        long long gstride = (long long)gridDim.x * blockDim.x;
        for (long long i = ntiles * TILE_V4 + gtid; i < nvec; i += gstride) {
            vf4 a = x4[i];
            vf4 b = y4[i];
            #pragma unroll
            for (int k = 0; k < 4; ++k) {
                s += (a[k] > b[k]) ? (a[k] - b[k]) : 0.0f;  c += (a[k] > b[k]);
            }
        }
        if (gtid == 0) {
            for (long long j = nvec << 2; j < n; ++j) {
                float d = x[j] - y[j];
                if (x[j] > y[j]) { s += d; c += 1; }
            }
        }
    }

    // wave-64 shuffle reduction
    #pragma unroll
    for (int off = 32; off > 0; off >>= 1) {
        s += __shfl_down(s, off, 64);
        c += __shfl_down(c, off, 64);
    }

    __shared__ float ss[NTHREADS / 64];
    __shared__ int   sc[NTHREADS / 64];
    int lane = threadIdx.x & 63;
    int wave = threadIdx.x >> 6;
    if (lane == 0) { ss[wave] = s; sc[wave] = c; }
    __syncthreads();
    if (threadIdx.x == 0) {
        float ts = 0.0f; int tc = 0;
        #pragma unroll
        for (int w = 0; w < NTHREADS / 64; ++w) { ts += ss[w]; tc += sc[w]; }
        psum[blockIdx.x] = ts;
        pcnt[blockIdx.x] = tc;
    }
}

__global__ __launch_bounds__(1024) void loss1_final(
    const float* __restrict__ psum, const int* __restrict__ pcnt,
    int nparts, float* __restrict__ out) {
    int tid = threadIdx.x;
    float s = 0.0f;
    int c = 0;
    for (int i = tid; i < nparts; i += 1024) {
        s += psum[i];
        c += pcnt[i];
    }
    #pragma unroll
    for (int off = 32; off > 0; off >>= 1) {
        s += __shfl_down(s, off, 64);
        c += __shfl_down(c, off, 64);
    }
    __shared__ float ss[16];
    __shared__ int   sc[16];
    int lane = tid & 63;
    int wave = tid >> 6;
    if (lane == 0) { ss[wave] = s; sc[wave] = c; }
    __syncthreads();
    if (tid == 0) {
        float ts = 0.0f; int tc = 0;
        #pragma unroll
        for (int w = 0; w < 16; ++w) { ts += ss[w]; tc += sc[w]; }
        out[0] = (tc > 0) ? (ts / (float)tc) : 0.0f;
    }
}

extern "C" void kernel_launch(void* const* d_in, const int* in_sizes, int n_in,
                              void* d_out, int out_size, void* d_ws, size_t ws_size,
                              hipStream_t stream) {
    const float* x = (const float*)d_in[0];
    const float* y = (const float*)d_in[1];
    long long n = (long long)in_sizes[0];

    float* psum = (float*)d_ws;
    int*   pcnt = (int*)((char*)d_ws + NBLOCKS * sizeof(float));

    loss1_partial<<<NBLOCKS, NTHREADS, 0, stream>>>(x, y, n, psum, pcnt);
    loss1_final<<<1, 1024, 0, stream>>>(psum, pcnt, NBLOCKS, (float*)d_out);
}